// Round 1
// baseline (409.492 us; speedup 1.0000x reference)
//
#include <hip/hip_runtime.h>
#include <hip/hip_bf16.h>

#define BATCH_ 128
#define LOOK_  512
#define CH_    512
#define FC_    192

typedef __attribute__((ext_vector_type(4))) float  f32x4;
typedef __attribute__((ext_vector_type(8))) short  bf16x8;

__device__ __forceinline__ unsigned short f2bf(float f) {
  union { __hip_bfloat16 h; unsigned short u; } cv;
  cv.h = __float2bfloat16(f);
  return cv.u;
}

// ---------------------------------------------------------------------------
// Pass 1: nx = x - x[:, -1, :], cast bf16, transpose (B,L,C) -> nxT (C,B,L).
// Also emit normT (C,B) f32.
// Grid: (128 b, 8 l-tiles, 8 c-tiles), 256 threads. 64x64 tile.
// ---------------------------------------------------------------------------
__global__ __launch_bounds__(256) void nlinear_pass1(
    const float* __restrict__ x, __hip_bfloat16* __restrict__ nxT,
    float* __restrict__ normT) {
  const int b  = blockIdx.x;
  const int l0 = blockIdx.y * 64;
  const int c0 = blockIdx.z * 64;
  const int t  = threadIdx.x;

  __shared__ float norm_s[64];
  __shared__ __align__(16) unsigned short T[64][88];  // [c][l], stride 176B

  if (t < 64) norm_s[t] = x[((size_t)b * LOOK_ + (LOOK_ - 1)) * CH_ + c0 + t];
  __syncthreads();

  {
    const int rg   = t >> 4;      // 16 row-groups of 4 l-rows
    const int c4   = t & 15;      // 16 float4 column slots
    const int row0 = rg * 4;
    const int cc   = c4 * 4;
    float a[4][4];
#pragma unroll
    for (int j = 0; j < 4; ++j) {
      const float4 v = *(const float4*)&x[((size_t)b * LOOK_ + l0 + row0 + j) * CH_ + c0 + cc];
      a[j][0] = v.x; a[j][1] = v.y; a[j][2] = v.z; a[j][3] = v.w;
    }
#pragma unroll
    for (int i = 0; i < 4; ++i) {
      const float nm = norm_s[cc + i];
      ushort4 p;
      p.x = f2bf(a[0][i] - nm);
      p.y = f2bf(a[1][i] - nm);
      p.z = f2bf(a[2][i] - nm);
      p.w = f2bf(a[3][i] - nm);
      *(ushort4*)&T[cc + i][row0] = p;  // 8B store, stride 176B -> near-uniform banks
    }
  }
  __syncthreads();

#pragma unroll
  for (int r = 0; r < 2; ++r) {
    const int idx = t + r * 256;
    const int cc  = idx >> 3;
    const int lq  = idx & 7;
    const uint4 d = *(const uint4*)&T[cc][lq * 8];
    *(uint4*)&nxT[((size_t)(c0 + cc) * BATCH_ + b) * LOOK_ + l0 + lq * 8] = d;
  }

  if (blockIdx.y == 7 && t < 64) normT[(c0 + t) * BATCH_ + b] = norm_s[t];
}

// ---------------------------------------------------------------------------
// Pass 2: per-channel GEMM. 512 WGs (1 channel), 512 thr (8 waves, 2x4).
// Wave tile 64x48, mfma_f32_16x16x32_bf16, K-loop 8 x 64, double-buffered LDS.
// A via global_load_lds (source-side XOR-16B-granule swizzle), B f32->bf16
// reg-staged with the same swizzle on ds_write. Output to outT (C,F,B).
// ---------------------------------------------------------------------------
__global__ __launch_bounds__(512, 4) void nlinear_pass2(
    const __hip_bfloat16* __restrict__ nxT, const float* __restrict__ W,
    const float* __restrict__ bias, const float* __restrict__ normT,
    float* __restrict__ outT) {
  const int wg = blockIdx.x;
  const int c  = (wg & 7) * 64 + (wg >> 3);  // XCD-chunked channel assignment

  const int tid  = threadIdx.x;
  const int lane = tid & 63;
  const int w    = tid >> 6;
  const int wb0  = (w >> 2) * 64;   // wave batch origin (2 rows of waves)
  const int wf0  = (w & 3) * 48;    // wave forecast origin (4 cols of waves)
  const int ln   = lane & 15;
  const int lh   = lane >> 4;

  __shared__ __align__(16) unsigned short Ab[2][BATCH_ * 64]; // 16KB each
  __shared__ __align__(16) unsigned short Bb[2][FC_ * 64];    // 24KB each

  const __hip_bfloat16* nxT_c = nxT + (size_t)c * BATCH_ * LOOK_;
  const float*          W_c   = W   + (size_t)c * FC_ * LOOK_;

  f32x4 acc[4][3];
#pragma unroll
  for (int m = 0; m < 4; ++m)
#pragma unroll
    for (int n = 0; n < 3; ++n) acc[m][n] = (f32x4){0.f, 0.f, 0.f, 0.f};

  float4 bpre[3][2];

  auto stageA = [&](int l0, int buf) {
#pragma unroll
    for (int r = 0; r < 2; ++r) {
      const int gl  = tid + r * 512;
      const int row = gl >> 3;
      const int g   = gl & 7;
      const __hip_bfloat16* src = nxT_c + (size_t)row * LOOK_ + l0 + ((g ^ (row & 7)) * 8);
      unsigned short* dst = &Ab[buf][gl * 8];
      __builtin_amdgcn_global_load_lds(
          (const __attribute__((address_space(1))) unsigned int*)(const void*)src,
          (__attribute__((address_space(3))) unsigned int*)(void*)dst, 16, 0, 0);
    }
  };
  auto loadB = [&](int l0) {
#pragma unroll
    for (int r = 0; r < 3; ++r) {
      const int gl = tid + r * 512;
      const int f  = gl >> 3;
      const int g  = gl & 7;
      const float* src = W_c + (size_t)f * LOOK_ + l0 + g * 8;
      bpre[r][0] = *(const float4*)src;
      bpre[r][1] = *(const float4*)(src + 4);
    }
  };
  auto writeB = [&](int buf) {
#pragma unroll
    for (int r = 0; r < 3; ++r) {
      const int gl = tid + r * 512;
      const int f  = gl >> 3;
      const int g  = gl & 7;
      uint4 q;
      q.x = (unsigned)f2bf(bpre[r][0].x) | ((unsigned)f2bf(bpre[r][0].y) << 16);
      q.y = (unsigned)f2bf(bpre[r][0].z) | ((unsigned)f2bf(bpre[r][0].w) << 16);
      q.z = (unsigned)f2bf(bpre[r][1].x) | ((unsigned)f2bf(bpre[r][1].y) << 16);
      q.w = (unsigned)f2bf(bpre[r][1].z) | ((unsigned)f2bf(bpre[r][1].w) << 16);
      *(uint4*)&Bb[buf][f * 64 + ((g ^ (f & 7)) * 8)] = q;
    }
  };
  auto compute = [&](int buf) {
#pragma unroll
    for (int ks = 0; ks < 2; ++ks) {
      const int sg = (ks * 4 + lh) ^ (lane & 7);  // swizzled 16B granule
      bf16x8 af[4], bfr[3];
#pragma unroll
      for (int m = 0; m < 4; ++m)
        af[m] = *(const bf16x8*)&Ab[buf][(wb0 + m * 16 + ln) * 64 + sg * 8];
#pragma unroll
      for (int n = 0; n < 3; ++n)
        bfr[n] = *(const bf16x8*)&Bb[buf][(wf0 + n * 16 + ln) * 64 + sg * 8];
#pragma unroll
      for (int m = 0; m < 4; ++m)
#pragma unroll
        for (int n = 0; n < 3; ++n)
          acc[m][n] = __builtin_amdgcn_mfma_f32_16x16x32_bf16(af[m], bfr[n], acc[m][n], 0, 0, 0);
    }
  };

  // prologue: stage k-step 0
  stageA(0, 0);
  loadB(0);
  writeB(0);         // compiler inserts vmcnt wait for bpre data-dep
  __syncthreads();   // drains glds (vmcnt(0) before s_barrier)

  for (int k = 0; k < 8; ++k) {
    const int cur = k & 1, nxt = cur ^ 1;
    const bool pf = (k < 7);
    if (pf) {
      stageA((k + 1) * 64, nxt);  // async into other buffer
      loadB((k + 1) * 64);        // global -> regs, latency hides under compute
    }
    compute(cur);
    if (pf) writeB(nxt);
    __syncthreads();
  }

  // epilogue: + bias + norm, store to outT (C, F, B) -> coalesced float4
  float bv[3];
#pragma unroll
  for (int n = 0; n < 3; ++n) bv[n] = bias[c * FC_ + wf0 + n * 16 + ln];
#pragma unroll
  for (int m = 0; m < 4; ++m) {
    const int bb0 = wb0 + m * 16 + lh * 4;
    const float4 nm4 = *(const float4*)&normT[c * BATCH_ + bb0];
#pragma unroll
    for (int n = 0; n < 3; ++n) {
      const int ff = wf0 + n * 16 + ln;
      float4 res;
      res.x = acc[m][n][0] + bv[n] + nm4.x;
      res.y = acc[m][n][1] + bv[n] + nm4.y;
      res.z = acc[m][n][2] + bv[n] + nm4.z;
      res.w = acc[m][n][3] + bv[n] + nm4.w;
      *(float4*)&outT[((size_t)c * FC_ + ff) * BATCH_ + bb0] = res;
    }
  }
}

// ---------------------------------------------------------------------------
// Pass 3: transpose outT (C,F,B) -> out (B,F,C). Grid (192 f, 2 b, 8 c).
// ---------------------------------------------------------------------------
__global__ __launch_bounds__(256) void nlinear_pass3(
    const float* __restrict__ outT, float* __restrict__ out) {
  const int f  = blockIdx.x;
  const int b0 = blockIdx.y * 64;
  const int c0 = blockIdx.z * 64;
  const int t  = threadIdx.x;
  __shared__ __align__(16) float T[64][68];  // [c][b], stride 272B (16B-aligned rows)

#pragma unroll
  for (int r = 0; r < 4; ++r) {
    const int idx = t + r * 256;
    const int cc  = idx >> 4;
    const int b4  = idx & 15;
    const float4 v = *(const float4*)&outT[((size_t)(c0 + cc) * FC_ + f) * BATCH_ + b0 + b4 * 4];
    *(float4*)&T[cc][b4 * 4] = v;
  }
  __syncthreads();

#pragma unroll
  for (int r = 0; r < 4; ++r) {
    const int idx = t + r * 256;
    const int bb  = idx >> 4;
    const int c4  = idx & 15;
    float4 v;
    v.x = T[c4 * 4 + 0][bb];
    v.y = T[c4 * 4 + 1][bb];
    v.z = T[c4 * 4 + 2][bb];
    v.w = T[c4 * 4 + 3][bb];
    *(float4*)&out[((size_t)(b0 + bb) * FC_ + f) * CH_ + c0 + c4 * 4] = v;
  }
}

// ---------------------------------------------------------------------------
extern "C" void kernel_launch(void* const* d_in, const int* in_sizes, int n_in,
                              void* d_out, int out_size, void* d_ws, size_t ws_size,
                              hipStream_t stream) {
  const float* x    = (const float*)d_in[0];
  const float* W    = (const float*)d_in[1];
  const float* bias = (const float*)d_in[2];
  float* out        = (float*)d_out;

  // workspace layout: nxT bf16 (64 MiB) | normT f32 (256 KiB) | outT f32 (48 MiB)
  __hip_bfloat16* nxT = (__hip_bfloat16*)d_ws;
  float* normT = (float*)((char*)d_ws + (size_t)CH_ * BATCH_ * LOOK_ * 2);
  float* outT  = (float*)((char*)normT + (size_t)CH_ * BATCH_ * 4);

  hipLaunchKernelGGL(nlinear_pass1, dim3(BATCH_, 8, 8), dim3(256), 0, stream,
                     x, nxT, normT);
  hipLaunchKernelGGL(nlinear_pass2, dim3(512), dim3(512), 0, stream,
                     nxT, W, bias, normT, outT);
  hipLaunchKernelGGL(nlinear_pass3, dim3(FC_, 2, 8), dim3(256), 0, stream,
                     outT, out);
}